// Round 15
// baseline (210.625 us; speedup 1.0000x reference)
//
#include <hip/hip_runtime.h>
#include <hip/hip_bf16.h>

typedef __hip_bfloat16 bf16;
typedef __attribute__((ext_vector_type(8))) short s8v;   // 8 bf16 MFMA A/B frag
typedef __attribute__((ext_vector_type(4))) float f4v;   // MFMA C/D frag

#define D_MODEL 1024
#define S_LEN   2048
#define BATCH   2
#define NH      16
#define HD      64
#define M_TOTAL 4096
#define NT      (S_LEN / 64)

// ---- async global->LDS, 16B per lane; LDS dest = uniform base + lane*16 ----
__device__ __forceinline__ void gll16(const bf16* g, bf16* l) {
    __builtin_amdgcn_global_load_lds(
        (const __attribute__((address_space(1))) void*)g,
        (__attribute__((address_space(3))) void*)l, 16, 0, 0);
}

// ---------------- fp32 -> bf16 converts (single fused launch, r10-verified) ----------------
struct CvtPtrs {
    const float* sx; bf16* dx;                       // x: 2048 blocks
    const float* s0; const float* s1; const float* s2; const float* s3;
    bf16* d0; bf16* d1; bf16* d2; bf16* d3;          // 4 weights: 512 blocks each
};

__global__ __launch_bounds__(256) void cvt_all(CvtPtrs p) {
    const int bid = blockIdx.x;
    const float* s; bf16* d; int i;
    if (bid < 2048) {
        s = p.sx; d = p.dx;
        i = (bid * 256 + threadIdx.x) * 8;
    } else {
        const int wsel = (bid - 2048) >> 9;          // 512 blocks per weight
        const int wb   = (bid - 2048) & 511;
        s = (wsel == 0) ? p.s0 : (wsel == 1) ? p.s1 : (wsel == 2) ? p.s2 : p.s3;
        d = (wsel == 0) ? p.d0 : (wsel == 1) ? p.d1 : (wsel == 2) ? p.d2 : p.d3;
        i = (wb * 256 + threadIdx.x) * 8;
    }
    float4 a = *(const float4*)(s + i);
    float4 b = *(const float4*)(s + i + 4);
    union { bf16 h[8]; uint4 u; } q;
    q.h[0] = __float2bfloat16(a.x); q.h[1] = __float2bfloat16(a.y);
    q.h[2] = __float2bfloat16(a.z); q.h[3] = __float2bfloat16(a.w);
    q.h[4] = __float2bfloat16(b.x); q.h[5] = __float2bfloat16(b.y);
    q.h[6] = __float2bfloat16(b.z); q.h[7] = __float2bfloat16(b.w);
    *(uint4*)(d + i) = q.u;
}

// ---------------- GEMM main loop: 2-phase double-buffered (r4-verified) ----------------
template<int TM, int TN>
__device__ __forceinline__ void gemm_main(const bf16* __restrict__ A,
                                          const bf16* __restrict__ W,
                                          bf16* As, bf16* Bs,     // each [2][T*32]
                                          int bm, int bn,
                                          f4v (&acc)[TM/32][TN/32])
{
    constexpr int FM = TM / 32, FN = TN / 32;
    constexpr int CALLS_A = TM / 16, CALLS = (TM + TN) / 16, PW = CALLS / 4;
    const int t = threadIdx.x, wv = t >> 6, lane = t & 63;
    const int quad = lane >> 4, l15 = lane & 15;
    const int wm = (wv >> 1) * (TM / 2), wn = (wv & 1) * (TN / 2);
    const int lr = lane >> 2, lc = (lane & 3) * 8;

    auto STAGE = [&](int buf, int k0) {
        #pragma unroll
        for (int c = 0; c < PW; ++c) {
            const int cc = wv * PW + c;
            if (cc < CALLS_A) {
                gll16(A + (size_t)(bm + cc * 16 + lr) * D_MODEL + k0 + lc,
                      As + buf * (TM * 32) + cc * 16 * 32);
            } else {
                const int r2 = cc - CALLS_A;
                gll16(W + (size_t)(bn + r2 * 16 + lr) * D_MODEL + k0 + lc,
                      Bs + buf * (TN * 32) + r2 * 16 * 32);
            }
        }
    };

    STAGE(0, 0);
    __syncthreads();
    int cur = 0;

    for (int k0 = 0; k0 < D_MODEL; k0 += 32) {
        if (k0 + 32 < D_MODEL) STAGE(cur ^ 1, k0 + 32);

        const bf16* ab = As + cur * (TM * 32);
        const bf16* bb = Bs + cur * (TN * 32);
        s8v af[FM], bfv[FN];
        #pragma unroll
        for (int i = 0; i < FM; ++i)
            af[i] = *(const s8v*)(ab + (wm + i * 16 + l15) * 32 + quad * 8);
        #pragma unroll
        for (int j = 0; j < FN; ++j)
            bfv[j] = *(const s8v*)(bb + (wn + j * 16 + l15) * 32 + quad * 8);
        __builtin_amdgcn_s_setprio(1);
        #pragma unroll
        for (int i = 0; i < FM; ++i)
            #pragma unroll
            for (int j = 0; j < FN; ++j)
                acc[i][j] = __builtin_amdgcn_mfma_f32_16x16x32_bf16(af[i], bfv[j], acc[i][j], 0, 0, 0);
        __builtin_amdgcn_s_setprio(0);

        __syncthreads();      // drains this wave's gll16 (vmcnt) + frag reads (lgkm)
        cur ^= 1;
    }
}

// Fused QKV: grid (8, 32, 3); z=0 Q, z=1 K ([b][h][s][d]); z=2 V^T ([b][h][d][s]).
__global__ __launch_bounds__(256) void gemm_qkv(
    const bf16* __restrict__ x,
    const bf16* __restrict__ Wq, const bf16* __restrict__ Wk, const bf16* __restrict__ Wv,
    const float* __restrict__ bq, const float* __restrict__ bk, const float* __restrict__ bv,
    bf16* __restrict__ Qb, bf16* __restrict__ Kb, bf16* __restrict__ Vtb)
{
    __shared__ __align__(16) char smem[4 * 64 * 72 * 2];   // 36864 B >= dbuf As+Bs (32768 B)
    bf16* As = (bf16*)smem;                                 // [2][128*32]
    bf16* Bs = (bf16*)(smem + 2 * 128 * 32 * 2);            // [2][128*32]
    bf16 (*Tw)[64][72] = (bf16(*)[64][72])smem;             // z==2 transpose staging

    const int z = blockIdx.z;
    const bf16*  W    = (z == 0) ? Wq : (z == 1) ? Wk : Wv;
    const float* bias = (z == 0) ? bq : (z == 1) ? bk : bv;
    bf16*        out  = (z == 0) ? Qb : (z == 1) ? Kb : Vtb;
    const int bm = blockIdx.y * 128, bn = blockIdx.x * 128;

    f4v acc[4][4] = {};
    gemm_main<128, 128>(x, W, As, Bs, bm, bn, acc);

    const int t = threadIdx.x, wv = t >> 6, lane = t & 63;
    const int quad = lane >> 4, l15 = lane & 15;
    const int wm = (wv >> 1) * 64, wn = (wv & 1) * 64;

    if (z == 2) {
        __syncthreads();   // all waves done with As/Bs before Tw overwrites them
        #pragma unroll
        for (int j = 0; j < 4; ++j) {
            const int col = bn + wn + j * 16 + l15;
            const float bv_ = bias[col];
            #pragma unroll
            for (int i = 0; i < 4; ++i) {
                #pragma unroll
                for (int rp = 0; rp < 4; rp += 2) {
                    union { bf16 h[2]; unsigned u; } p2;
                    p2.h[0] = __float2bfloat16(acc[i][j][rp]     + bv_);
                    p2.h[1] = __float2bfloat16(acc[i][j][rp + 1] + bv_);
                    *(unsigned*)&Tw[wv][j * 16 + l15][i * 16 + quad * 4 + rp] = p2.u;
                }
            }
        }
        // wave-local round-trip: compiler inserts lgkmcnt wait, no barrier needed
        const int bb = (bm + wm) >> 11, s0 = (bm + wm) & 2047;
        #pragma unroll
        for (int p = 0; p < 8; ++p) {
            const int dl = p * 8 + (lane >> 3);
            const int sl = (lane & 7) * 8;
            const int col = bn + wn + dl;
            const int h = col >> 6, d = col & 63;
            uint4 v = *(const uint4*)&Tw[wv][dl][sl];
            *(uint4*)&out[(((size_t)(bb * NH + h)) * HD + d) * S_LEN + s0 + sl] = v;
        }
    } else {
        #pragma unroll
        for (int j = 0; j < 4; ++j) {
            const int col = bn + wn + j * 16 + l15;
            const float bv_ = bias[col];
            const int h = col >> 6, d = col & 63;
            #pragma unroll
            for (int i = 0; i < 4; ++i) {
                #pragma unroll
                for (int r = 0; r < 4; ++r) {
                    const int row = bm + wm + i * 16 + quad * 4 + r;
                    const int b = row >> 11, s = row & 2047;
                    const float v = acc[i][j][r] + bv_;
                    out[(((size_t)(b * NH + h)) * S_LEN + s) * HD + d] = __float2bfloat16(v);
                }
            }
        }
    }
}

// Output projection: 64x128 tiles -> grid (8, 64) = 512 blocks. fp32 out.
__global__ __launch_bounds__(256) void gemm_out(
    const bf16* __restrict__ Ob, const bf16* __restrict__ Wo,
    const float* __restrict__ bo, float* __restrict__ out)
{
    __shared__ __align__(16) bf16 As[2][64 * 32];
    __shared__ __align__(16) bf16 Bs[2][128 * 32];
    const int bm = blockIdx.y * 64, bn = blockIdx.x * 128;

    f4v acc[2][4] = {};
    gemm_main<64, 128>(Ob, Wo, &As[0][0], &Bs[0][0], bm, bn, acc);

    const int t = threadIdx.x, wv = t >> 6, lane = t & 63;
    const int quad = lane >> 4, l15 = lane & 15;
    const int wm = (wv >> 1) * 32, wn = (wv & 1) * 64;
    #pragma unroll
    for (int j = 0; j < 4; ++j) {
        const int col = bn + wn + j * 16 + l15;
        const float bv_ = bo[col];
        #pragma unroll
        for (int i = 0; i < 2; ++i)
            #pragma unroll
            for (int r = 0; r < 4; ++r) {
                const int row = bm + wm + i * 16 + quad * 4 + r;
                out[(size_t)row * D_MODEL + col] = acc[i][j][r] + bv_;
            }
    }
}

// ---------------- Flash attention: r14 + QBLK=128 (32 q-rows per wave) ----------------
// Amortization move: each wave reuses the SAME K/V LDS fragments for TWO q-tiles
// (q = base+l15 and base+16+l15). K/V LDS reads per FLOP halve; block count halves
// (512) so per-CU staging bytes + barrier windows halve; MFMA/softmax per FLOP
// unchanged. Same verified swizzle algebra (row 16+l15 has same sw: 16 = 0 mod 8);
// same 2-barrier staged loop, mbias prologue (r13), XCD-local decode (r14).
// Softmax state duplicated per tile (mprev0/1, lsum0/1).
// LDS = 8K(Ks)+8K(Vts)+16K(Ps[4][32][64])+8K(mbias) = 40960 B.
__global__ __launch_bounds__(256) void attn_mfma(
    const bf16* __restrict__ Q, const bf16* __restrict__ K,
    const bf16* __restrict__ Vt, const int* __restrict__ mask,
    bf16* __restrict__ O)
{
    __shared__ __align__(16) bf16 Ks[64][64];
    __shared__ __align__(16) bf16 Vts[64][64];
    __shared__ __align__(16) bf16 Ps[4][32][64];   // per-wave P round-trip, swizzled
    __shared__ __align__(16) float mbias[S_LEN];   // additive mask bias (log2 domain)

    const int t = threadIdx.x, wv = t >> 6, lane = t & 63;
    const int quad = lane >> 4, l15 = lane & 15;
    const int sw = l15 & 7;
    const int bid = blockIdx.x;
    const int b = bid & 1, h = (bid >> 1) & 15, qt = bid >> 5;   // XCD-local (b,h); qt in [0,16)
    const int q0 = qt * 128;
    const size_t qkbase = ((size_t)(b * NH + h)) * S_LEN * HD;
    const size_t vtbase = ((size_t)(b * NH + h)) * HD * S_LEN;

    const float KSC  = 0.125f * 1.44269504f;   // scale * log2(e)
    const float THR2 = 8.0f * 1.44269504f;     // defer-max threshold (log2 domain)

    // Q fragments for both q-tiles (loop-invariant), straight from global
    const bf16* qrow0 = Q + qkbase + (size_t)(q0 + wv * 32 + l15) * HD;
    const bf16* qrow1 = qrow0 + (size_t)16 * HD;
    const s8v qf0 = *(const s8v*)(qrow0 + quad * 8);
    const s8v qf1 = *(const s8v*)(qrow0 + 32 + quad * 8);
    const s8v qf2 = *(const s8v*)(qrow1 + quad * 8);
    const s8v qf3 = *(const s8v*)(qrow1 + 32 + quad * 8);

    // ---- prologue: mask -> additive-bias LDS table (one pass, 8 ints/thread) ----
    #pragma unroll
    for (int i = 0; i < S_LEN / 256; ++i) {
        const int idx = i * 256 + t;
        mbias[idx] = mask[b * S_LEN + idx] ? 0.f : -1e30f;
    }

    // staging geometry: lane -> row srow = t>>2 (0..63), 32B = chunks c2,c2+1
    const int srow = t >> 2;
    const int swr  = srow & 7;
    const int c2   = (t & 3) * 2;                       // first 16B chunk (0,2,4,6)
    const int ch0  = c2 ^ swr, ch1 = (c2 + 1) ^ swr;    // swizzled LDS chunks

    uint4 kr0, kr1, vr0, vr1;
    auto LOADT = [&](int kt2) {
        const int kk = kt2 * 64;
        const uint4* kp = (const uint4*)(K  + qkbase + (size_t)(kk + srow) * HD + c2 * 8);
        const uint4* vp = (const uint4*)(Vt + vtbase + (size_t)srow * S_LEN + kk + c2 * 8);
        kr0 = kp[0]; kr1 = kp[1];
        vr0 = vp[0]; vr1 = vp[1];
    };
    auto STAGE = [&]() {
        *(uint4*)&Ks[srow][ch0 * 8]  = kr0;
        *(uint4*)&Ks[srow][ch1 * 8]  = kr1;
        *(uint4*)&Vts[srow][ch0 * 8] = vr0;
        *(uint4*)&Vts[srow][ch1 * 8] = vr1;
    };

    LOADT(0);

    float mprev0 = -1e30f, lsum0 = 0.f;   // per-lane state: tile0 q = base+l15
    float mprev1 = -1e30f, lsum1 = 0.f;   // tile1 q = base+16+l15
    f4v oacc0[4] = {};
    f4v oacc1[4] = {};

    for (int kt = 0; kt < NT; ++kt) {
        const int k0 = kt * 64;
        __syncthreads();                       // prev-iter LDS reads done (+mbias vis @kt=0)
        STAGE();
        __syncthreads();
        if (kt + 1 < NT) LOADT(kt + 1);        // overlap with compute below

        // ---- S^T tiles for both q-tiles: K frags read ONCE, used twice ----
        f4v st0[4], st1[4];
        __builtin_amdgcn_s_setprio(1);
        #pragma unroll
        for (int c = 0; c < 4; ++c) {
            const char* kr = (const char*)&Ks[c * 16 + l15][0];
            s8v kf0 = *(const s8v*)(kr + ((quad ^ sw) << 4));
            s8v kf1 = *(const s8v*)(kr + (((4 + quad) ^ sw) << 4));
            f4v z0 = {0.f, 0.f, 0.f, 0.f};
            z0 = __builtin_amdgcn_mfma_f32_16x16x32_bf16(kf0, qf0, z0, 0, 0, 0);
            z0 = __builtin_amdgcn_mfma_f32_16x16x32_bf16(kf1, qf1, z0, 0, 0, 0);
            st0[c] = z0;
            f4v z1 = {0.f, 0.f, 0.f, 0.f};
            z1 = __builtin_amdgcn_mfma_f32_16x16x32_bf16(kf0, qf2, z1, 0, 0, 0);
            z1 = __builtin_amdgcn_mfma_f32_16x16x32_bf16(kf1, qf3, z1, 0, 0, 0);
            st1[c] = z1;
        }
        __builtin_amdgcn_s_setprio(0);

        // ---- scale + mask bias from LDS; running max per tile ----
        float mt0 = -1e30f, mt1 = -1e30f;
        #pragma unroll
        for (int c = 0; c < 4; ++c) {
            const f4v m4 = *(const f4v*)&mbias[k0 + c * 16 + quad * 4];
            st0[c] = st0[c] * KSC + m4;
            st1[c] = st1[c] * KSC + m4;
            mt0 = fmaxf(mt0, fmaxf(fmaxf(st0[c][0], st0[c][1]), fmaxf(st0[c][2], st0[c][3])));
            mt1 = fmaxf(mt1, fmaxf(fmaxf(st1[c][0], st1[c][1]), fmaxf(st1[c][2], st1[c][3])));
        }
        mt0 = fmaxf(mt0, __shfl_xor(mt0, 16, 64));
        mt0 = fmaxf(mt0, __shfl_xor(mt0, 32, 64));
        mt1 = fmaxf(mt1, __shfl_xor(mt1, 16, 64));
        mt1 = fmaxf(mt1, __shfl_xor(mt1, 32, 64));

        // ---- defer-max rescale, per tile ----
        float mn0 = mprev0;
        if (!__all(mt0 <= mprev0 + THR2)) {
            mn0 = fmaxf(mprev0, mt0);
            const float alpha = __builtin_amdgcn_exp2f(mprev0 - mn0);
            mprev0 = mn0;
            float av[4];
            #pragma unroll
            for (int r = 0; r < 4; ++r) av[r] = __shfl(alpha, quad * 4 + r, 64);
            #pragma unroll
            for (int dt = 0; dt < 4; ++dt)
                #pragma unroll
                for (int r = 0; r < 4; ++r) oacc0[dt][r] *= av[r];
            lsum0 *= alpha;
        }
        float mn1 = mprev1;
        if (!__all(mt1 <= mprev1 + THR2)) {
            mn1 = fmaxf(mprev1, mt1);
            const float alpha = __builtin_amdgcn_exp2f(mprev1 - mn1);
            mprev1 = mn1;
            float av[4];
            #pragma unroll
            for (int r = 0; r < 4; ++r) av[r] = __shfl(alpha, quad * 4 + r, 64);
            #pragma unroll
            for (int dt = 0; dt < 4; ++dt)
                #pragma unroll
                for (int r = 0; r < 4; ++r) oacc1[dt][r] *= av[r];
            lsum1 *= alpha;
        }

        f4v ps0 = {0.f, 0.f, 0.f, 0.f}, ps1 = {0.f, 0.f, 0.f, 0.f};
        #pragma unroll
        for (int c = 0; c < 4; ++c) {
            f4v e0 = st0[c] - mn0;
            e0[0] = __builtin_amdgcn_exp2f(e0[0]);
            e0[1] = __builtin_amdgcn_exp2f(e0[1]);
            e0[2] = __builtin_amdgcn_exp2f(e0[2]);
            e0[3] = __builtin_amdgcn_exp2f(e0[3]);
            st0[c] = e0; ps0 += e0;
            f4v e1 = st1[c] - mn1;
            e1[0] = __builtin_amdgcn_exp2f(e1[0]);
            e1[1] = __builtin_amdgcn_exp2f(e1[1]);
            e1[2] = __builtin_amdgcn_exp2f(e1[2]);
            e1[3] = __builtin_amdgcn_exp2f(e1[3]);
            st1[c] = e1; ps1 += e1;
        }
        lsum0 += ps0[0] + ps0[1] + ps0[2] + ps0[3];
        lsum1 += ps1[0] + ps1[1] + ps1[2] + ps1[3];

        // ---- P -> LDS per-wave, both tiles (rows l15 and 16+l15 share sw) ----
        char* pr0 = (char*)&Ps[wv][l15][0];
        char* pr1 = (char*)&Ps[wv][16 + l15][0];
        #pragma unroll
        for (int c = 0; c < 4; ++c) {
            union { bf16 hh[4]; short4 s4; } pk0, pk1;
            pk0.hh[0] = __float2bfloat16(st0[c][0]);
            pk0.hh[1] = __float2bfloat16(st0[c][1]);
            pk0.hh[2] = __float2bfloat16(st0[c][2]);
            pk0.hh[3] = __float2bfloat16(st0[c][3]);
            pk1.hh[0] = __float2bfloat16(st1[c][0]);
            pk1.hh[1] = __float2bfloat16(st1[c][1]);
            pk1.hh[2] = __float2bfloat16(st1[c][2]);
            pk1.hh[3] = __float2bfloat16(st1[c][3]);
            const int wch = (2 * c + (quad >> 1)) ^ sw;
            *(short4*)(pr0 + (wch << 4) + ((quad & 1) << 3)) = pk0.s4;
            *(short4*)(pr1 + (wch << 4) + ((quad & 1) << 3)) = pk1.s4;
        }
        s8v pfA0 = *(const s8v*)(pr0 + ((quad ^ sw) << 4));
        s8v pfA1 = *(const s8v*)(pr0 + (((4 + quad) ^ sw) << 4));
        s8v pfB0 = *(const s8v*)(pr1 + ((quad ^ sw) << 4));
        s8v pfB1 = *(const s8v*)(pr1 + (((4 + quad) ^ sw) << 4));

        // ---- O += P V : V frags read ONCE, used for both tiles ----
        __builtin_amdgcn_s_setprio(1);
        #pragma unroll
        for (int dt = 0; dt < 4; ++dt) {
            const char* vr = (const char*)&Vts[dt * 16 + l15][0];
            s8v vf0 = *(const s8v*)(vr + ((quad ^ sw) << 4));
            s8v vf1 = *(const s8v*)(vr + (((4 + quad) ^ sw) << 4));
            oacc0[dt] = __builtin_amdgcn_mfma_f32_16x16x32_bf16(pfA0, vf0, oacc0[dt], 0, 0, 0);
            oacc0[dt] = __builtin_amdgcn_mfma_f32_16x16x32_bf16(pfA1, vf1, oacc0[dt], 0, 0, 0);
            oacc1[dt] = __builtin_amdgcn_mfma_f32_16x16x32_bf16(pfB0, vf0, oacc1[dt], 0, 0, 0);
            oacc1[dt] = __builtin_amdgcn_mfma_f32_16x16x32_bf16(pfB1, vf1, oacc1[dt], 0, 0, 0);
        }
        __builtin_amdgcn_s_setprio(0);
    }

    // ---- epilogue: finish lsum reductions, then O[b][s][h*64+d], both tiles ----
    lsum0 += __shfl_xor(lsum0, 16, 64);
    lsum0 += __shfl_xor(lsum0, 32, 64);
    lsum1 += __shfl_xor(lsum1, 16, 64);
    lsum1 += __shfl_xor(lsum1, 32, 64);
    float linv0[4], linv1[4];
    #pragma unroll
    for (int r = 0; r < 4; ++r) {
        linv0[r] = 1.f / __shfl(lsum0, quad * 4 + r, 64);
        linv1[r] = 1.f / __shfl(lsum1, quad * 4 + r, 64);
    }
    const int sbase = q0 + wv * 32;
    #pragma unroll
    for (int dt = 0; dt < 4; ++dt) {
        const int col = h * 64 + dt * 16 + l15;
        #pragma unroll
        for (int r = 0; r < 4; ++r) {
            const int s0r = sbase + quad * 4 + r;
            O[((size_t)b * S_LEN + s0r) * D_MODEL + col] =
                __float2bfloat16(oacc0[dt][r] * linv0[r]);
            const int s1r = sbase + 16 + quad * 4 + r;
            O[((size_t)b * S_LEN + s1r) * D_MODEL + col] =
                __float2bfloat16(oacc1[dt][r] * linv1[r]);
        }
    }
}

extern "C" void kernel_launch(void* const* d_in, const int* in_sizes, int n_in,
                              void* d_out, int out_size, void* d_ws, size_t ws_size,
                              hipStream_t stream) {
    const float* x    = (const float*)d_in[0];
    const int*   mask = (const int*)  d_in[1];
    const float* Wq   = (const float*)d_in[2];
    const float* bq   = (const float*)d_in[3];
    const float* Wk   = (const float*)d_in[4];
    const float* bk   = (const float*)d_in[5];
    const float* Wv   = (const float*)d_in[6];
    const float* bv   = (const float*)d_in[7];
    const float* Wo   = (const float*)d_in[8];
    const float* bo   = (const float*)d_in[9];
    float* out = (float*)d_out;

    char* w = (char*)d_ws;
    bf16* xb  = (bf16*)w; w += (size_t)M_TOTAL * D_MODEL * 2;
    bf16* Wqb = (bf16*)w; w += (size_t)D_MODEL * D_MODEL * 2;
    bf16* Wkb = (bf16*)w; w += (size_t)D_MODEL * D_MODEL * 2;
    bf16* Wvb = (bf16*)w; w += (size_t)D_MODEL * D_MODEL * 2;
    bf16* Wob = (bf16*)w; w += (size_t)D_MODEL * D_MODEL * 2;
    bf16* Qb  = (bf16*)w; w += (size_t)M_TOTAL * D_MODEL * 2;   // [b][h][s][d]
    bf16* Kb  = (bf16*)w; w += (size_t)M_TOTAL * D_MODEL * 2;   // [b][h][s][d]
    bf16* Vtb = (bf16*)w; w += (size_t)M_TOTAL * D_MODEL * 2;   // [b][h][d][s]
    bf16* Ob  = (bf16*)w; w += (size_t)M_TOTAL * D_MODEL * 2;   // [b][s][1024]

    CvtPtrs cp = { x, xb, Wq, Wk, Wv, Wo, Wqb, Wkb, Wvb, Wob };
    cvt_all<<<4096, 256, 0, stream>>>(cp);

    gemm_qkv<<<dim3(8, 32, 3), 256, 0, stream>>>(xb, Wqb, Wkb, Wvb, bq, bk, bv, Qb, Kb, Vtb);

    attn_mfma<<<BATCH * NH * (S_LEN / 128), 256, 0, stream>>>(Qb, Kb, Vtb, mask, Ob);

    gemm_out<<<dim3(8, 64), 256, 0, stream>>>(Ob, Wob, bo, out);
}

// Round 16
// 202.815 us; speedup vs baseline: 1.0385x; 1.0385x over previous
//
#include <hip/hip_runtime.h>
#include <hip/hip_bf16.h>

typedef __hip_bfloat16 bf16;
typedef __attribute__((ext_vector_type(8))) short s8v;   // 8 bf16 MFMA A/B frag
typedef __attribute__((ext_vector_type(4))) float f4v;   // MFMA C/D frag

#define D_MODEL 1024
#define S_LEN   2048
#define BATCH   2
#define NH      16
#define HD      64
#define M_TOTAL 4096
#define NT      (S_LEN / 64)

// ---- async global->LDS, 16B per lane; LDS dest = uniform base + lane*16 ----
__device__ __forceinline__ void gll16(const bf16* g, bf16* l) {
    __builtin_amdgcn_global_load_lds(
        (const __attribute__((address_space(1))) void*)g,
        (__attribute__((address_space(3))) void*)l, 16, 0, 0);
}

// ---------------- fp32 -> bf16 converts (single fused launch, r10-verified) ----------------
struct CvtPtrs {
    const float* sx; bf16* dx;                       // x: 2048 blocks
    const float* s0; const float* s1; const float* s2; const float* s3;
    bf16* d0; bf16* d1; bf16* d2; bf16* d3;          // 4 weights: 512 blocks each
};

__global__ __launch_bounds__(256) void cvt_all(CvtPtrs p) {
    const int bid = blockIdx.x;
    const float* s; bf16* d; int i;
    if (bid < 2048) {
        s = p.sx; d = p.dx;
        i = (bid * 256 + threadIdx.x) * 8;
    } else {
        const int wsel = (bid - 2048) >> 9;          // 512 blocks per weight
        const int wb   = (bid - 2048) & 511;
        s = (wsel == 0) ? p.s0 : (wsel == 1) ? p.s1 : (wsel == 2) ? p.s2 : p.s3;
        d = (wsel == 0) ? p.d0 : (wsel == 1) ? p.d1 : (wsel == 2) ? p.d2 : p.d3;
        i = (wb * 256 + threadIdx.x) * 8;
    }
    float4 a = *(const float4*)(s + i);
    float4 b = *(const float4*)(s + i + 4);
    union { bf16 h[8]; uint4 u; } q;
    q.h[0] = __float2bfloat16(a.x); q.h[1] = __float2bfloat16(a.y);
    q.h[2] = __float2bfloat16(a.z); q.h[3] = __float2bfloat16(a.w);
    q.h[4] = __float2bfloat16(b.x); q.h[5] = __float2bfloat16(b.y);
    q.h[6] = __float2bfloat16(b.z); q.h[7] = __float2bfloat16(b.w);
    *(uint4*)(d + i) = q.u;
}

// ---------------- GEMM main loop: 2-phase double-buffered (r4-verified) ----------------
template<int TM, int TN>
__device__ __forceinline__ void gemm_main(const bf16* __restrict__ A,
                                          const bf16* __restrict__ W,
                                          bf16* As, bf16* Bs,     // each [2][T*32]
                                          int bm, int bn,
                                          f4v (&acc)[TM/32][TN/32])
{
    constexpr int FM = TM / 32, FN = TN / 32;
    constexpr int CALLS_A = TM / 16, CALLS = (TM + TN) / 16, PW = CALLS / 4;
    const int t = threadIdx.x, wv = t >> 6, lane = t & 63;
    const int quad = lane >> 4, l15 = lane & 15;
    const int wm = (wv >> 1) * (TM / 2), wn = (wv & 1) * (TN / 2);
    const int lr = lane >> 2, lc = (lane & 3) * 8;

    auto STAGE = [&](int buf, int k0) {
        #pragma unroll
        for (int c = 0; c < PW; ++c) {
            const int cc = wv * PW + c;
            if (cc < CALLS_A) {
                gll16(A + (size_t)(bm + cc * 16 + lr) * D_MODEL + k0 + lc,
                      As + buf * (TM * 32) + cc * 16 * 32);
            } else {
                const int r2 = cc - CALLS_A;
                gll16(W + (size_t)(bn + r2 * 16 + lr) * D_MODEL + k0 + lc,
                      Bs + buf * (TN * 32) + r2 * 16 * 32);
            }
        }
    };

    STAGE(0, 0);
    __syncthreads();
    int cur = 0;

    for (int k0 = 0; k0 < D_MODEL; k0 += 32) {
        if (k0 + 32 < D_MODEL) STAGE(cur ^ 1, k0 + 32);

        const bf16* ab = As + cur * (TM * 32);
        const bf16* bb = Bs + cur * (TN * 32);
        s8v af[FM], bfv[FN];
        #pragma unroll
        for (int i = 0; i < FM; ++i)
            af[i] = *(const s8v*)(ab + (wm + i * 16 + l15) * 32 + quad * 8);
        #pragma unroll
        for (int j = 0; j < FN; ++j)
            bfv[j] = *(const s8v*)(bb + (wn + j * 16 + l15) * 32 + quad * 8);
        __builtin_amdgcn_s_setprio(1);
        #pragma unroll
        for (int i = 0; i < FM; ++i)
            #pragma unroll
            for (int j = 0; j < FN; ++j)
                acc[i][j] = __builtin_amdgcn_mfma_f32_16x16x32_bf16(af[i], bfv[j], acc[i][j], 0, 0, 0);
        __builtin_amdgcn_s_setprio(0);

        __syncthreads();      // drains this wave's gll16 (vmcnt) + frag reads (lgkm)
        cur ^= 1;
    }
}

// Fused QKV: grid (8, 32, 3); z=0 Q, z=1 K ([b][h][s][d]); z=2 V^T ([b][h][d][s]).
// ALL epilogues now coalesced via Tw staging (z=2: transposed [d][s]; z<2: [s][d]
// — each wave's 64-col slice is exactly one head, rows 128B-contiguous).
__global__ __launch_bounds__(256) void gemm_qkv(
    const bf16* __restrict__ x,
    const bf16* __restrict__ Wq, const bf16* __restrict__ Wk, const bf16* __restrict__ Wv,
    const float* __restrict__ bq, const float* __restrict__ bk, const float* __restrict__ bv,
    bf16* __restrict__ Qb, bf16* __restrict__ Kb, bf16* __restrict__ Vtb)
{
    __shared__ __align__(16) char smem[4 * 64 * 72 * 2];   // 36864 B >= dbuf As+Bs (32768 B)
    bf16* As = (bf16*)smem;                                 // [2][128*32]
    bf16* Bs = (bf16*)(smem + 2 * 128 * 32 * 2);            // [2][128*32]
    bf16 (*Tw)[64][72] = (bf16(*)[64][72])smem;             // epilogue staging overlay

    const int z = blockIdx.z;
    const bf16*  W    = (z == 0) ? Wq : (z == 1) ? Wk : Wv;
    const float* bias = (z == 0) ? bq : (z == 1) ? bk : bv;
    bf16*        out  = (z == 0) ? Qb : (z == 1) ? Kb : Vtb;
    const int bm = blockIdx.y * 128, bn = blockIdx.x * 128;

    f4v acc[4][4] = {};
    gemm_main<128, 128>(x, W, As, Bs, bm, bn, acc);

    const int t = threadIdx.x, wv = t >> 6, lane = t & 63;
    const int quad = lane >> 4, l15 = lane & 15;
    const int wm = (wv >> 1) * 64, wn = (wv & 1) * 64;

    __syncthreads();   // all waves past last gemm barrier; safe to overlay As/Bs

    if (z == 2) {
        // ---- stage bias-added tile TRANSPOSED into per-wave LDS [d][s] ----
        #pragma unroll
        for (int j = 0; j < 4; ++j) {
            const int col = bn + wn + j * 16 + l15;
            const float bv_ = bias[col];
            #pragma unroll
            for (int i = 0; i < 4; ++i) {
                #pragma unroll
                for (int rp = 0; rp < 4; rp += 2) {
                    union { bf16 h[2]; unsigned u; } p2;
                    p2.h[0] = __float2bfloat16(acc[i][j][rp]     + bv_);
                    p2.h[1] = __float2bfloat16(acc[i][j][rp + 1] + bv_);
                    *(unsigned*)&Tw[wv][j * 16 + l15][i * 16 + quad * 4 + rp] = p2.u;
                }
            }
        }
        // wave-local round-trip: compiler inserts lgkmcnt wait, no barrier needed
        const int bb = (bm + wm) >> 11, s0 = (bm + wm) & 2047;
        #pragma unroll
        for (int p = 0; p < 8; ++p) {
            const int dl = p * 8 + (lane >> 3);
            const int sl = (lane & 7) * 8;
            const int col = bn + wn + dl;
            const int h = col >> 6, d = col & 63;
            uint4 v = *(const uint4*)&Tw[wv][dl][sl];
            *(uint4*)&out[(((size_t)(bb * NH + h)) * HD + d) * S_LEN + s0 + sl] = v;
        }
    } else {
        // ---- stage bias-added tile [row][col] into per-wave LDS ----
        #pragma unroll
        for (int j = 0; j < 4; ++j) {
            const int col = bn + wn + j * 16 + l15;
            const float bv_ = bias[col];
            #pragma unroll
            for (int i = 0; i < 4; ++i) {
                #pragma unroll
                for (int r = 0; r < 4; ++r) {
                    Tw[wv][i * 16 + quad * 4 + r][j * 16 + l15] =
                        __float2bfloat16(acc[i][j][r] + bv_);
                }
            }
        }
        // wave's 64 cols = one head (bn,wn multiples of 64); rows 128B-contiguous
        const int hh = (bn + wn) >> 6;
        const int bb = (bm + wm) >> 11, s0 = (bm + wm) & 2047;
        const size_t obase = (((size_t)(bb * NH + hh)) * S_LEN + s0) * HD;
        #pragma unroll
        for (int p = 0; p < 8; ++p) {
            const int rl = p * 8 + (lane >> 3);
            const int dl = (lane & 7) * 8;
            uint4 v = *(const uint4*)&Tw[wv][rl][dl];
            *(uint4*)&out[obase + (size_t)rl * HD + dl] = v;
        }
    }
}

// Output projection: 64x128 tiles -> grid (8, 64) = 512 blocks. fp32 out.
__global__ __launch_bounds__(256) void gemm_out(
    const bf16* __restrict__ Ob, const bf16* __restrict__ Wo,
    const float* __restrict__ bo, float* __restrict__ out)
{
    __shared__ __align__(16) bf16 As[2][64 * 32];
    __shared__ __align__(16) bf16 Bs[2][128 * 32];
    const int bm = blockIdx.y * 64, bn = blockIdx.x * 128;

    f4v acc[2][4] = {};
    gemm_main<64, 128>(Ob, Wo, &As[0][0], &Bs[0][0], bm, bn, acc);

    const int t = threadIdx.x, wv = t >> 6, lane = t & 63;
    const int quad = lane >> 4, l15 = lane & 15;
    const int wm = (wv >> 1) * 32, wn = (wv & 1) * 64;
    #pragma unroll
    for (int j = 0; j < 4; ++j) {
        const int col = bn + wn + j * 16 + l15;
        const float bv_ = bo[col];
        #pragma unroll
        for (int i = 0; i < 2; ++i)
            #pragma unroll
            for (int r = 0; r < 4; ++r) {
                const int row = bm + wm + i * 16 + quad * 4 + r;
                out[(size_t)row * D_MODEL + col] = acc[i][j][r] + bv_;
            }
    }
}

// ---------------- Flash attention: r14 (74.1us, verified best) ----------------
// 2-barrier staged loop, reg-prefetch LOADT(kt+1), unpadded XOR-swizzled LDS,
// mask->bias LDS prologue (keeps mask off vmcnt path - the r13 +26us fix),
// XCD-local decode (K/V L2-resident, FETCH 12.4 MB).
// LDS = 8K(Ks)+8K(Vts)+8K(Ps)+8K(mbias) = 32768 B -> 4 blocks/CU.
__global__ __launch_bounds__(256) void attn_mfma(
    const bf16* __restrict__ Q, const bf16* __restrict__ K,
    const bf16* __restrict__ Vt, const int* __restrict__ mask,
    bf16* __restrict__ O)
{
    __shared__ __align__(16) bf16 Ks[64][64];
    __shared__ __align__(16) bf16 Vts[64][64];
    __shared__ __align__(16) bf16 Ps[4][16][64];   // per-wave P round-trip, swizzled
    __shared__ __align__(16) float mbias[S_LEN];   // additive mask bias (log2 domain)

    const int t = threadIdx.x, wv = t >> 6, lane = t & 63;
    const int quad = lane >> 4, l15 = lane & 15;
    const int sw = l15 & 7;
    const int bid = blockIdx.x;
    const int b = bid & 1, h = (bid >> 1) & 15, qt = bid >> 5;   // XCD-local (b,h)
    const int q0 = qt * 64;
    const size_t qkbase = ((size_t)(b * NH + h)) * S_LEN * HD;
    const size_t vtbase = ((size_t)(b * NH + h)) * HD * S_LEN;

    const float KSC  = 0.125f * 1.44269504f;   // scale * log2(e)
    const float THR2 = 8.0f * 1.44269504f;     // defer-max threshold (log2 domain)

    // Q fragments (loop-invariant), straight from global
    const bf16* qrow = Q + qkbase + (size_t)(q0 + wv * 16 + l15) * HD;
    const s8v qf0 = *(const s8v*)(qrow + quad * 8);
    const s8v qf1 = *(const s8v*)(qrow + 32 + quad * 8);

    // ---- prologue: mask -> additive-bias LDS table (one pass, 8 ints/thread) ----
    #pragma unroll
    for (int i = 0; i < S_LEN / 256; ++i) {
        const int idx = i * 256 + t;
        mbias[idx] = mask[b * S_LEN + idx] ? 0.f : -1e30f;
    }

    // staging geometry: lane -> row srow = t>>2 (0..63), 32B = chunks c2,c2+1
    const int srow = t >> 2;
    const int swr  = srow & 7;
    const int c2   = (t & 3) * 2;                       // first 16B chunk (0,2,4,6)
    const int ch0  = c2 ^ swr, ch1 = (c2 + 1) ^ swr;    // swizzled LDS chunks

    uint4 kr0, kr1, vr0, vr1;
    auto LOADT = [&](int kt2) {
        const int kk = kt2 * 64;
        const uint4* kp = (const uint4*)(K  + qkbase + (size_t)(kk + srow) * HD + c2 * 8);
        const uint4* vp = (const uint4*)(Vt + vtbase + (size_t)srow * S_LEN + kk + c2 * 8);
        kr0 = kp[0]; kr1 = kp[1];
        vr0 = vp[0]; vr1 = vp[1];
    };
    auto STAGE = [&]() {
        *(uint4*)&Ks[srow][ch0 * 8]  = kr0;
        *(uint4*)&Ks[srow][ch1 * 8]  = kr1;
        *(uint4*)&Vts[srow][ch0 * 8] = vr0;
        *(uint4*)&Vts[srow][ch1 * 8] = vr1;
    };

    LOADT(0);

    float mprev = -1e30f, lsum = 0.f;   // per-lane state for q = l15 (lsum partial)
    f4v oacc[4] = {};

    for (int kt = 0; kt < NT; ++kt) {
        const int k0 = kt * 64;
        __syncthreads();                       // prev-iter LDS reads done (+mbias vis @kt=0)
        STAGE();
        __syncthreads();
        if (kt + 1 < NT) LOADT(kt + 1);        // overlap with compute below

        // ---- S^T tiles: rows = k-local, cols = q (swizzled reads) ----
        f4v st[4];
        __builtin_amdgcn_s_setprio(1);
        #pragma unroll
        for (int c = 0; c < 4; ++c) {
            const char* kr = (const char*)&Ks[c * 16 + l15][0];
            s8v kf0 = *(const s8v*)(kr + ((quad ^ sw) << 4));
            s8v kf1 = *(const s8v*)(kr + (((4 + quad) ^ sw) << 4));
            f4v z = {0.f, 0.f, 0.f, 0.f};
            z = __builtin_amdgcn_mfma_f32_16x16x32_bf16(kf0, qf0, z, 0, 0, 0);
            z = __builtin_amdgcn_mfma_f32_16x16x32_bf16(kf1, qf1, z, 0, 0, 0);
            st[c] = z;
        }
        __builtin_amdgcn_s_setprio(0);

        // ---- scale + mask bias from LDS (lgkmcnt only, no vmcnt drain); max ----
        float mt = -1e30f;
        #pragma unroll
        for (int c = 0; c < 4; ++c) {
            const f4v m4 = *(const f4v*)&mbias[k0 + c * 16 + quad * 4];
            st[c] = st[c] * KSC + m4;
            mt = fmaxf(mt, fmaxf(fmaxf(st[c][0], st[c][1]), fmaxf(st[c][2], st[c][3])));
        }
        mt = fmaxf(mt, __shfl_xor(mt, 16, 64));   // cross-quad: full 64-k max
        mt = fmaxf(mt, __shfl_xor(mt, 32, 64));

        // ---- defer-max rescale ----
        float mn = mprev;
        if (!__all(mt <= mprev + THR2)) {
            mn = fmaxf(mprev, mt);
            const float alpha = __builtin_amdgcn_exp2f(mprev - mn);
            mprev = mn;
            float av[4];
            #pragma unroll
            for (int r = 0; r < 4; ++r) av[r] = __shfl(alpha, quad * 4 + r, 64);
            #pragma unroll
            for (int dt = 0; dt < 4; ++dt)
                #pragma unroll
                for (int r = 0; r < 4; ++r) oacc[dt][r] *= av[r];
            lsum *= alpha;
        }

        f4v psv = {0.f, 0.f, 0.f, 0.f};
        #pragma unroll
        for (int c = 0; c < 4; ++c) {
            f4v e = st[c] - mn;
            e[0] = __builtin_amdgcn_exp2f(e[0]);
            e[1] = __builtin_amdgcn_exp2f(e[1]);
            e[2] = __builtin_amdgcn_exp2f(e[2]);
            e[3] = __builtin_amdgcn_exp2f(e[3]);
            st[c] = e;
            psv += e;
        }
        lsum += psv[0] + psv[1] + psv[2] + psv[3];

        // ---- P -> LDS [q][k] per-wave (swizzled b64 writes), read back as A-frag ----
        char* pr = (char*)&Ps[wv][l15][0];
        #pragma unroll
        for (int c = 0; c < 4; ++c) {
            union { bf16 hh[4]; short4 s4; } pk;
            pk.hh[0] = __float2bfloat16(st[c][0]);
            pk.hh[1] = __float2bfloat16(st[c][1]);
            pk.hh[2] = __float2bfloat16(st[c][2]);
            pk.hh[3] = __float2bfloat16(st[c][3]);
            const int wch = (2 * c + (quad >> 1)) ^ sw;
            *(short4*)(pr + (wch << 4) + ((quad & 1) << 3)) = pk.s4;
        }
        s8v pf0 = *(const s8v*)(pr + ((quad ^ sw) << 4));
        s8v pf1 = *(const s8v*)(pr + (((4 + quad) ^ sw) << 4));

        // ---- O += P V ----
        __builtin_amdgcn_s_setprio(1);
        #pragma unroll
        for (int dt = 0; dt < 4; ++dt) {
            const char* vr = (const char*)&Vts[dt * 16 + l15][0];
            s8v vf0 = *(const s8v*)(vr + ((quad ^ sw) << 4));
            s8v vf1 = *(const s8v*)(vr + (((4 + quad) ^ sw) << 4));
            oacc[dt] = __builtin_amdgcn_mfma_f32_16x16x32_bf16(pf0, vf0, oacc[dt], 0, 0, 0);
            oacc[dt] = __builtin_amdgcn_mfma_f32_16x16x32_bf16(pf1, vf1, oacc[dt], 0, 0, 0);
        }
        __builtin_amdgcn_s_setprio(0);
    }

    // ---- epilogue: finish lsum reduction, then O[b][s][h*64+d] ----
    lsum += __shfl_xor(lsum, 16, 64);
    lsum += __shfl_xor(lsum, 32, 64);
    float linv[4];
    #pragma unroll
    for (int r = 0; r < 4; ++r) linv[r] = 1.f / __shfl(lsum, quad * 4 + r, 64);
    #pragma unroll
    for (int dt = 0; dt < 4; ++dt) {
        #pragma unroll
        for (int r = 0; r < 4; ++r) {
            const int s = q0 + wv * 16 + quad * 4 + r;
            const int col = h * 64 + dt * 16 + l15;
            O[((size_t)b * S_LEN + s) * D_MODEL + col] = __float2bfloat16(oacc[dt][r] * linv[r]);
        }
    }
}

extern "C" void kernel_launch(void* const* d_in, const int* in_sizes, int n_in,
                              void* d_out, int out_size, void* d_ws, size_t ws_size,
                              hipStream_t stream) {
    const float* x    = (const float*)d_in[0];
    const int*   mask = (const int*)  d_in[1];
    const float* Wq   = (const float*)d_in[2];
    const float* bq   = (const float*)d_in[3];
    const float* Wk   = (const float*)d_in[4];
    const float* bk   = (const float*)d_in[5];
    const float* Wv   = (const float*)d_in[6];
    const float* bv   = (const float*)d_in[7];
    const float* Wo   = (const float*)d_in[8];
    const float* bo   = (const float*)d_in[9];
    float* out = (float*)d_out;

    char* w = (char*)d_ws;
    bf16* xb  = (bf16*)w; w += (size_t)M_TOTAL * D_MODEL * 2;
    bf16* Wqb = (bf16*)w; w += (size_t)D_MODEL * D_MODEL * 2;
    bf16* Wkb = (bf16*)w; w += (size_t)D_MODEL * D_MODEL * 2;
    bf16* Wvb = (bf16*)w; w += (size_t)D_MODEL * D_MODEL * 2;
    bf16* Wob = (bf16*)w; w += (size_t)D_MODEL * D_MODEL * 2;
    bf16* Qb  = (bf16*)w; w += (size_t)M_TOTAL * D_MODEL * 2;   // [b][h][s][d]
    bf16* Kb  = (bf16*)w; w += (size_t)M_TOTAL * D_MODEL * 2;   // [b][h][s][d]
    bf16* Vtb = (bf16*)w; w += (size_t)M_TOTAL * D_MODEL * 2;   // [b][h][d][s]
    bf16* Ob  = (bf16*)w; w += (size_t)M_TOTAL * D_MODEL * 2;   // [b][s][1024]

    CvtPtrs cp = { x, xb, Wq, Wk, Wv, Wo, Wqb, Wkb, Wvb, Wob };
    cvt_all<<<4096, 256, 0, stream>>>(cp);

    gemm_qkv<<<dim3(8, 32, 3), 256, 0, stream>>>(xb, Wqb, Wkb, Wvb, bq, bk, bv, Qb, Kb, Vtb);

    attn_mfma<<<BATCH * NH * (S_LEN / 64), 256, 0, stream>>>(Qb, Kb, Vtb, mask, Ob);

    gemm_out<<<dim3(8, 64), 256, 0, stream>>>(Ob, Wob, bo, out);
}